// Round 1
// baseline (341.001 us; speedup 1.0000x reference)
//
#include <hip/hip_runtime.h>
#include <math.h>

typedef unsigned short u16;
typedef unsigned int u32;
typedef short bf4 __attribute__((ext_vector_type(4)));
typedef float f4 __attribute__((ext_vector_type(4)));

#define SEQ 2048
#define HID 2880
#define QKVN 5120

static __device__ __forceinline__ u16 f2bf(float x) {
  union { float f; u32 u; } v; v.f = x;
  u32 r = v.u + 0x7fffu + ((v.u >> 16) & 1u);
  return (u16)(r >> 16);
}
static __device__ __forceinline__ float bf2f(u16 s) {
  union { u32 u; float f; } v; v.u = ((u32)s) << 16;
  return v.f;
}
static __device__ __forceinline__ void gl_lds16(const void* g, void* l) {
  __builtin_amdgcn_global_load_lds((const __attribute__((address_space(1))) u32*)g,
                                   (__attribute__((address_space(3))) u32*)l, 16, 0, 0);
}
#define MFMA(a, b, c) __builtin_amdgcn_mfma_f32_16x16x16bf16_1k(a, b, c, 0, 0, 0)

// ---------------- RMSNorm: x[2048][2880] f32 -> t bf16 ----------------
__global__ __launch_bounds__(256) void k_rmsnorm(const float* __restrict__ x,
                                                 const float* __restrict__ w,
                                                 u16* __restrict__ t) {
  const int row = blockIdx.x;
  const float* xr = x + (size_t)row * HID;
  float ss = 0.f;
  for (int i = threadIdx.x; i < 720; i += 256) {
    float4 v = ((const float4*)xr)[i];
    ss += v.x * v.x + v.y * v.y + v.z * v.z + v.w * v.w;
  }
#pragma unroll
  for (int m = 1; m < 64; m <<= 1) ss += __shfl_xor(ss, m);
  __shared__ float red[4];
  if ((threadIdx.x & 63) == 0) red[threadIdx.x >> 6] = ss;
  __syncthreads();
  float sc = rsqrtf((red[0] + red[1] + red[2] + red[3]) * (1.0f / HID) + 1e-5f);
  u16* tr = t + (size_t)row * HID;
  for (int i = threadIdx.x; i < 720; i += 256) {
    float4 v = ((const float4*)xr)[i];
    float4 wv = ((const float4*)w)[i];
    ushort4 o;
    o.x = f2bf(v.x * sc * wv.x);
    o.y = f2bf(v.y * sc * wv.y);
    o.z = f2bf(v.z * sc * wv.z);
    o.w = f2bf(v.w * sc * wv.w);
    ((ushort4*)tr)[i] = o;
  }
}

// ------- transpose+convert: W[K][N] f32 -> WT[N][K] bf16 (64x64 tiles) -------
__global__ __launch_bounds__(256) void k_convT(const float* __restrict__ W,
                                               u16* __restrict__ WT, int K, int N) {
  __shared__ u16 tile[64][65];  // [n_local][k_local]
  const int n0 = blockIdx.x * 64, k0 = blockIdx.y * 64;
  for (int s = threadIdx.x; s < 1024; s += 256) {
    int r = s >> 4, c4 = (s & 15) * 4;
    float4 v = *(const float4*)&W[(size_t)(k0 + r) * N + n0 + c4];
    tile[c4 + 0][r] = f2bf(v.x);
    tile[c4 + 1][r] = f2bf(v.y);
    tile[c4 + 2][r] = f2bf(v.z);
    tile[c4 + 3][r] = f2bf(v.w);
  }
  __syncthreads();
  for (int s = threadIdx.x; s < 512; s += 256) {
    int r = s >> 3, c8 = (s & 7) * 8;
    u32 p0 = tile[r][c8 + 0] | ((u32)tile[r][c8 + 1] << 16);
    u32 p1 = tile[r][c8 + 2] | ((u32)tile[r][c8 + 3] << 16);
    u32 p2 = tile[r][c8 + 4] | ((u32)tile[r][c8 + 5] << 16);
    u32 p3 = tile[r][c8 + 6] | ((u32)tile[r][c8 + 7] << 16);
    *(uint4*)&WT[(size_t)(n0 + r) * K + k0 + c8] = make_uint4(p0, p1, p2, p3);
  }
}

// ---------------- GEMM: C[M][N] = A[M][K]bf16 * (BT[N][K])^T ----------------
// 128x128 tile, BK=64, 4 waves (2x2), 16x16x16 MFMA, gload_lds w/ XOR chunk swizzle.
template <int MODE>  // 0: store bf16 ; 1: store f32 + residual, guard col<N
__global__ __launch_bounds__(256) void k_gemm(const u16* __restrict__ A,
                                              const u16* __restrict__ BT,
                                              void* __restrict__ Cv,
                                              const float* __restrict__ resid,
                                              int M, int N, int K) {
  __shared__ u16 lA[128 * 64];
  __shared__ u16 lB[128 * 64];
  const int m0 = blockIdx.x * 128, n0 = blockIdx.y * 128;
  const int tid = threadIdx.x;
  const int l = tid & 63, w = tid >> 6;
  const int wm = (w >> 1) * 64, wn = (w & 1) * 64;
  const int g = l >> 4, q = l & 15;
  f4 acc[4][4] = {};
  for (int k0 = 0; k0 < K; k0 += 64) {
    __syncthreads();  // prev tile reads done before overwrite
#pragma unroll
    for (int p = 0; p < 4; ++p) {
      int slot = p * 256 + tid;
      int row = slot >> 3, c = slot & 7;
      int sc = c ^ (row & 7);  // pre-swizzled global source, linear LDS dest
      gl_lds16(A + (size_t)(m0 + row) * K + k0 + sc * 8, (char*)lA + slot * 16);
    }
#pragma unroll
    for (int p = 0; p < 4; ++p) {
      int slot = p * 256 + tid;
      int row = slot >> 3, c = slot & 7;
      int sc = c ^ (row & 7);
      gl_lds16(BT + (size_t)(n0 + row) * K + k0 + sc * 8, (char*)lB + slot * 16);
    }
    __syncthreads();  // compiler drains vmcnt before barrier
#pragma unroll
    for (int ks = 0; ks < 4; ++ks) {
      bf4 af[4], bfr[4];
      const int kb = ks * 16 + g * 4;
      const int kc = kb >> 3;
      const int klo = (kb & 7) * 2;
#pragma unroll
      for (int mt = 0; mt < 4; ++mt) {
        int row = wm + mt * 16 + q;
        af[mt] = *(const bf4*)((const char*)lA + row * 128 + ((kc ^ (row & 7)) << 4) + klo);
      }
#pragma unroll
      for (int nt = 0; nt < 4; ++nt) {
        int row = wn + nt * 16 + q;
        bfr[nt] = *(const bf4*)((const char*)lB + row * 128 + ((kc ^ (row & 7)) << 4) + klo);
      }
#pragma unroll
      for (int mt = 0; mt < 4; ++mt)
#pragma unroll
        for (int nt = 0; nt < 4; ++nt)
          acc[mt][nt] = MFMA(af[mt], bfr[nt], acc[mt][nt]);
    }
  }
#pragma unroll
  for (int mt = 0; mt < 4; ++mt)
#pragma unroll
    for (int nt = 0; nt < 4; ++nt)
#pragma unroll
      for (int r = 0; r < 4; ++r) {
        int row = m0 + wm + mt * 16 + g * 4 + r;
        int col = n0 + wn + nt * 16 + q;
        if constexpr (MODE == 0) {
          ((u16*)Cv)[(size_t)row * N + col] = f2bf(acc[mt][nt][r]);
        } else {
          if (col < N)
            ((float*)Cv)[(size_t)row * N + col] =
                acc[mt][nt][r] + resid[(size_t)row * N + col];
        }
      }
}

// ---------------- RoPE (YaRN/NTK): qkv bf16 -> qr[64][2048][64], kr[8][2048][64] ----
__global__ __launch_bounds__(256) void k_rope(const u16* __restrict__ qkv,
                                              u16* __restrict__ qrp,
                                              u16* __restrict__ krp) {
  const int t = blockIdx.y;
  const int i = blockIdx.x * 256 + threadIdx.x;  // [0, 2304) = 72 heads * 32 pairs
  const int d = i & 31, hd = i >> 5;
  const float low = 8.0927791f, high = 17.3980236f, conc = 1.3465735903f;
  float freq = powf(150000.0f, (float)d * (1.0f / 32.0f));
  float r01 = fminf(fmaxf(((float)d - low) / (high - low), 0.f), 1.f);
  float invf = (1.0f / (32.0f * freq)) * r01 + (1.0f / freq) * (1.f - r01);
  float ang = (float)t * invf;
  float cc = cosf(ang) * conc;
  float ss = sinf(ang) * conc;
  const u16* src = qkv + (size_t)t * QKVN + (hd < 64 ? hd * 64 : 4096 + (hd - 64) * 64);
  u16* dst = (hd < 64) ? (qrp + ((size_t)hd * SEQ + t) * 64)
                       : (krp + ((size_t)(hd - 64) * SEQ + t) * 64);
  float x1 = bf2f(src[d]), x2 = bf2f(src[d + 32]);
  dst[d] = f2bf(x1 * cc - x2 * ss);
  dst[d + 32] = f2bf(x2 * cc + x1 * ss);
}

// ---------------- V transpose: qkv v-cols -> vt[8][64][2048] bf16 ----------------
__global__ __launch_bounds__(256) void k_vtrans(const u16* __restrict__ qkv,
                                                u16* __restrict__ vt) {
  __shared__ u16 tile[64][72];  // [t_local][d]
  const int t0 = blockIdx.x * 64, h = blockIdx.y;
  for (int s = threadIdx.x; s < 512; s += 256) {
    int r = s >> 3, c8 = (s & 7) * 8;
    uint4 v = *(const uint4*)&qkv[(size_t)(t0 + r) * QKVN + 4608 + h * 64 + c8];
    *(uint4*)&tile[r][c8] = v;
  }
  __syncthreads();
  for (int s = threadIdx.x; s < 512; s += 256) {
    int d = s >> 3, c8 = (s & 7) * 8;
    u32 p0 = tile[c8 + 0][d] | ((u32)tile[c8 + 1][d] << 16);
    u32 p1 = tile[c8 + 2][d] | ((u32)tile[c8 + 3][d] << 16);
    u32 p2 = tile[c8 + 4][d] | ((u32)tile[c8 + 5][d] << 16);
    u32 p3 = tile[c8 + 6][d] | ((u32)tile[c8 + 7][d] << 16);
    *(uint4*)&vt[((size_t)h * 64 + d) * SEQ + t0 + c8] = make_uint4(p0, p1, p2, p3);
  }
}

// ---------------- Attention: sliding window 128 + sink, GQA 8x8 ----------------
// grid (128 qblocks of 16 tokens, 8 kv heads), 512 threads = 8 waves = 8 q-heads.
__global__ __launch_bounds__(512) void k_attn(const u16* __restrict__ qr,
                                              const u16* __restrict__ kr,
                                              const u16* __restrict__ vt,
                                              const float* __restrict__ sinks,
                                              u16* __restrict__ attn) {
  __shared__ u16 lK[144 * 72];       // [key][dim], stride 72
  __shared__ u16 lV[64 * 152];       // [dim][key], stride 152
  __shared__ u16 lP[8 * 16 * 148];   // per-wave [q][key], stride 148
  const int t0 = blockIdx.x * 16;
  const int h = blockIdx.y;
  const int j0 = t0 - 128;
  const int tid = threadIdx.x;
  // stage K rows (zero for j<0)
  for (int s = tid; s < 1152; s += 512) {
    int row = s >> 3, c = s & 7;
    int j = j0 + row;
    uint4 v = make_uint4(0, 0, 0, 0);
    if (j >= 0) v = *(const uint4*)&kr[((size_t)h * SEQ + j) * 64 + c * 8];
    *(uint4*)&lK[row * 72 + c * 8] = v;
  }
  // stage V^T rows (dims), 18 chunks of 8 keys
  for (int s = tid; s < 1152; s += 512) {
    int d = s / 18, c = s - d * 18;
    int jb = j0 + c * 8;
    uint4 v = make_uint4(0, 0, 0, 0);
    if (jb >= 0) v = *(const uint4*)&vt[((size_t)h * 64 + d) * SEQ + jb];
    *(uint4*)&lV[d * 152 + c * 8] = v;
  }
  __syncthreads();
  const int w = tid >> 6, l = tid & 63;
  const int g = l >> 4, q = l & 15;
  const int hq = h * 8 + w;
  const float sink = sinks[hq];
  bf4 qf[4];
  const u16* qrow = qr + ((size_t)hq * SEQ + t0 + q) * 64;
#pragma unroll
  for (int ks = 0; ks < 4; ++ks) qf[ks] = *(const bf4*)&qrow[ks * 16 + g * 4];
  // S = Q K^T over 9 key tiles
  f4 sacc[9];
#pragma unroll
  for (int nt = 0; nt < 9; ++nt) {
    f4 z = {0.f, 0.f, 0.f, 0.f};
    sacc[nt] = z;
#pragma unroll
    for (int ks = 0; ks < 4; ++ks) {
      bf4 kf = *(const bf4*)&lK[(nt * 16 + q) * 72 + ks * 16 + g * 4];
      sacc[nt] = MFMA(qf[ks], kf, sacc[nt]);
    }
  }
  const float NEG = -__builtin_inff();
  float rmax[4] = {NEG, NEG, NEG, NEG};
#pragma unroll
  for (int nt = 0; nt < 9; ++nt)
#pragma unroll
    for (int r = 0; r < 4; ++r) {
      float sv = sacc[nt][r] * 0.125f;
      int it = t0 + g * 4 + r;
      int j = j0 + nt * 16 + q;
      bool ban = (j > it) || (it - j >= 128) || (j < 0);
      sv = ban ? NEG : sv;
      sacc[nt][r] = sv;
      rmax[r] = fmaxf(rmax[r], sv);
    }
#pragma unroll
  for (int r = 0; r < 4; ++r)
#pragma unroll
    for (int m = 1; m < 16; m <<= 1) rmax[r] = fmaxf(rmax[r], __shfl_xor(rmax[r], m));
  float ssum[4];
  u16* pbase = lP + w * (16 * 148);
#pragma unroll
  for (int r = 0; r < 4; ++r) {
    float mf = fmaxf(rmax[r], sink);
    float ps = 0.f;
#pragma unroll
    for (int nt = 0; nt < 9; ++nt) {
      float p = __expf(sacc[nt][r] - mf);  // exp(-inf) = 0 for banned
      pbase[(g * 4 + r) * 148 + nt * 16 + q] = f2bf(p);
      ps += p;
    }
#pragma unroll
    for (int m = 1; m < 16; m <<= 1) ps += __shfl_xor(ps, m);
    ssum[r] = ps + __expf(sink - mf);  // sink joins the denominator only
  }
  // O = P V  (per-wave LDS, same-wave ordering => no barrier)
  f4 oacc[4] = {};
#pragma unroll
  for (int kt = 0; kt < 9; ++kt) {
    bf4 pa = *(const bf4*)&pbase[q * 148 + kt * 16 + g * 4];
#pragma unroll
    for (int nt = 0; nt < 4; ++nt) {
      bf4 vf = *(const bf4*)&lV[(nt * 16 + q) * 152 + kt * 16 + g * 4];
      oacc[nt] = MFMA(pa, vf, oacc[nt]);
    }
  }
#pragma unroll
  for (int nt = 0; nt < 4; ++nt)
#pragma unroll
    for (int r = 0; r < 4; ++r) {
      int row = t0 + g * 4 + r;
      attn[(size_t)row * 4096 + hq * 64 + nt * 16 + q] = f2bf(oacc[nt][r] / ssum[r]);
    }
}

extern "C" void kernel_launch(void* const* d_in, const int* in_sizes, int n_in,
                              void* d_out, int out_size, void* d_ws, size_t ws_size,
                              hipStream_t stream) {
  const float* x = (const float*)d_in[0];
  const float* norm_w = (const float*)d_in[1];
  const float* qkv_w = (const float*)d_in[2];
  const float* out_w = (const float*)d_in[3];
  const float* sinks = (const float*)d_in[4];
  float* out = (float*)d_out;
  char* ws = (char*)d_ws;
  // ws layout (bytes); attn aliases wqkvT (dead after QKV GEMM). total ~107.3 MB
  u16* t     = (u16*)(ws);                  // 2048*2880*2 = 11,796,480
  u16* wqkvT = (u16*)(ws + 11796480);       // 5120*2880*2 = 29,491,200
  u16* woutT = (u16*)(ws + 41287680);       // 2944*4096*2 = 24,117,248 (rows 2880..2943 pad)
  u16* qkv   = (u16*)(ws + 65404928);       // 2048*5120*2 = 20,971,520
  u16* qr    = (u16*)(ws + 86376448);       // 64*2048*64*2 = 16,777,216
  u16* kr    = (u16*)(ws + 103153664);      // 8*2048*64*2 = 2,097,152
  u16* vt    = (u16*)(ws + 105250816);      // 8*64*2048*2 = 2,097,152 -> end 107,347,968
  u16* attn  = (u16*)(ws + 11796480);       // alias wqkvT, 2048*4096*2 = 16,777,216

  k_rmsnorm<<<dim3(2048), dim3(256), 0, stream>>>(x, norm_w, t);
  k_convT<<<dim3(80, 45), dim3(256), 0, stream>>>(qkv_w, wqkvT, 2880, 5120);
  k_convT<<<dim3(45, 64), dim3(256), 0, stream>>>(out_w, woutT, 4096, 2880);
  k_gemm<0><<<dim3(16, 40), dim3(256), 0, stream>>>(t, wqkvT, (void*)qkv, nullptr,
                                                    2048, 5120, 2880);
  k_rope<<<dim3(9, 2048), dim3(256), 0, stream>>>(qkv, qr, kr);
  k_vtrans<<<dim3(32, 8), dim3(256), 0, stream>>>(qkv, vt);
  k_attn<<<dim3(128, 8), dim3(512), 0, stream>>>(qr, kr, vt, sinks, attn);
  k_gemm<1><<<dim3(16, 23), dim3(256), 0, stream>>>(attn, woutT, (void*)out, x,
                                                    2048, 2880, 4096);
}

// Round 2
// 241.068 us; speedup vs baseline: 1.4145x; 1.4145x over previous
//
#include <hip/hip_runtime.h>
#include <math.h>

typedef unsigned short u16;
typedef unsigned int u32;
typedef short bf4 __attribute__((ext_vector_type(4)));
typedef __bf16 bfv8 __attribute__((ext_vector_type(8)));
typedef float f4 __attribute__((ext_vector_type(4)));

#define SEQ 2048
#define HID 2880
#define QKVN 5120

static __device__ __forceinline__ u16 f2bf(float x) {
  union { float f; u32 u; } v; v.f = x;
  u32 r = v.u + 0x7fffu + ((v.u >> 16) & 1u);
  return (u16)(r >> 16);
}
static __device__ __forceinline__ float bf2f(u16 s) {
  union { u32 u; float f; } v; v.u = ((u32)s) << 16;
  return v.f;
}
static __device__ __forceinline__ void gl_lds16(const void* g, void* l) {
  __builtin_amdgcn_global_load_lds((const __attribute__((address_space(1))) u32*)g,
                                   (__attribute__((address_space(3))) u32*)l, 16, 0, 0);
}
#define MFMA(a, b, c) __builtin_amdgcn_mfma_f32_16x16x16bf16_1k(a, b, c, 0, 0, 0)
#define MFMA32(a, b, c) __builtin_amdgcn_mfma_f32_16x16x32_bf16(a, b, c, 0, 0, 0)

// ---------------- RMSNorm: x[2048][2880] f32 -> t bf16 ----------------
__global__ __launch_bounds__(256) void k_rmsnorm(const float* __restrict__ x,
                                                 const float* __restrict__ w,
                                                 u16* __restrict__ t) {
  const int row = blockIdx.x;
  const float* xr = x + (size_t)row * HID;
  float ss = 0.f;
  for (int i = threadIdx.x; i < 720; i += 256) {
    float4 v = ((const float4*)xr)[i];
    ss += v.x * v.x + v.y * v.y + v.z * v.z + v.w * v.w;
  }
#pragma unroll
  for (int m = 1; m < 64; m <<= 1) ss += __shfl_xor(ss, m);
  __shared__ float red[4];
  if ((threadIdx.x & 63) == 0) red[threadIdx.x >> 6] = ss;
  __syncthreads();
  float sc = rsqrtf((red[0] + red[1] + red[2] + red[3]) * (1.0f / HID) + 1e-5f);
  u16* tr = t + (size_t)row * HID;
  for (int i = threadIdx.x; i < 720; i += 256) {
    float4 v = ((const float4*)xr)[i];
    float4 wv = ((const float4*)w)[i];
    ushort4 o;
    o.x = f2bf(v.x * sc * wv.x);
    o.y = f2bf(v.y * sc * wv.y);
    o.z = f2bf(v.z * sc * wv.z);
    o.w = f2bf(v.w * sc * wv.w);
    ((ushort4*)tr)[i] = o;
  }
}

// ------- transpose+convert: W[K][N] f32 -> WT[N][K] bf16 (64x64 tiles) -------
__global__ __launch_bounds__(256) void k_convT(const float* __restrict__ W,
                                               u16* __restrict__ WT, int K, int N) {
  __shared__ u16 tile[64][65];  // [n_local][k_local]
  const int n0 = blockIdx.x * 64, k0 = blockIdx.y * 64;
  for (int s = threadIdx.x; s < 1024; s += 256) {
    int r = s >> 4, c4 = (s & 15) * 4;
    float4 v = *(const float4*)&W[(size_t)(k0 + r) * N + n0 + c4];
    tile[c4 + 0][r] = f2bf(v.x);
    tile[c4 + 1][r] = f2bf(v.y);
    tile[c4 + 2][r] = f2bf(v.z);
    tile[c4 + 3][r] = f2bf(v.w);
  }
  __syncthreads();
  for (int s = threadIdx.x; s < 512; s += 256) {
    int r = s >> 3, c8 = (s & 7) * 8;
    u32 p0 = tile[r][c8 + 0] | ((u32)tile[r][c8 + 1] << 16);
    u32 p1 = tile[r][c8 + 2] | ((u32)tile[r][c8 + 3] << 16);
    u32 p2 = tile[r][c8 + 4] | ((u32)tile[r][c8 + 5] << 16);
    u32 p3 = tile[r][c8 + 6] | ((u32)tile[r][c8 + 7] << 16);
    *(uint4*)&WT[(size_t)(n0 + r) * K + k0 + c8] = make_uint4(p0, p1, p2, p3);
  }
}

// ---------------- GEMM: C[M][N] = A[M][K]bf16 * (BT[N][K])^T ----------------
// 128x128 tile, BK=64, 4 waves (2x2), 16x16x32 MFMA, gload_lds w/ XOR chunk swizzle.
template <int MODE>  // 0: store bf16 ; 1: store f32 + residual, guard col<N
__global__ __launch_bounds__(256) void k_gemm(const u16* __restrict__ A,
                                              const u16* __restrict__ BT,
                                              void* __restrict__ Cv,
                                              const float* __restrict__ resid,
                                              int M, int N, int K) {
  __shared__ u16 lA[128 * 64];
  __shared__ u16 lB[128 * 64];
  const int m0 = blockIdx.x * 128, n0 = blockIdx.y * 128;
  const int tid = threadIdx.x;
  const int l = tid & 63, w = tid >> 6;
  const int wm = (w >> 1) * 64, wn = (w & 1) * 64;
  const int g = l >> 4, q = l & 15;
  f4 acc[4][4] = {};
  for (int k0 = 0; k0 < K; k0 += 64) {
    __syncthreads();  // prev tile reads done before overwrite
#pragma unroll
    for (int p = 0; p < 4; ++p) {
      int slot = p * 256 + tid;
      int row = slot >> 3, c = slot & 7;
      int sc = c ^ (row & 7);  // pre-swizzled global source, linear LDS dest
      gl_lds16(A + (size_t)(m0 + row) * K + k0 + sc * 8, (char*)lA + slot * 16);
    }
#pragma unroll
    for (int p = 0; p < 4; ++p) {
      int slot = p * 256 + tid;
      int row = slot >> 3, c = slot & 7;
      int sc = c ^ (row & 7);
      gl_lds16(BT + (size_t)(n0 + row) * K + k0 + sc * 8, (char*)lB + slot * 16);
    }
    __syncthreads();  // compiler drains vmcnt before barrier
#pragma unroll
    for (int ks = 0; ks < 2; ++ks) {
      bfv8 af[4], bfr[4];
      const int kc = ks * 4 + g;  // 16B chunk index within the 128B row
#pragma unroll
      for (int mt = 0; mt < 4; ++mt) {
        int row = wm + mt * 16 + q;
        af[mt] = *(const bfv8*)((const char*)lA + row * 128 + ((kc ^ (row & 7)) << 4));
      }
#pragma unroll
      for (int nt = 0; nt < 4; ++nt) {
        int row = wn + nt * 16 + q;
        bfr[nt] = *(const bfv8*)((const char*)lB + row * 128 + ((kc ^ (row & 7)) << 4));
      }
#pragma unroll
      for (int mt = 0; mt < 4; ++mt)
#pragma unroll
        for (int nt = 0; nt < 4; ++nt)
          acc[mt][nt] = MFMA32(af[mt], bfr[nt], acc[mt][nt]);
    }
  }
#pragma unroll
  for (int mt = 0; mt < 4; ++mt)
#pragma unroll
    for (int nt = 0; nt < 4; ++nt)
#pragma unroll
      for (int r = 0; r < 4; ++r) {
        int row = m0 + wm + mt * 16 + g * 4 + r;
        int col = n0 + wn + nt * 16 + q;
        if constexpr (MODE == 0) {
          ((u16*)Cv)[(size_t)row * N + col] = f2bf(acc[mt][nt][r]);
        } else {
          if (col < N)
            ((float*)Cv)[(size_t)row * N + col] =
                acc[mt][nt][r] + resid[(size_t)row * N + col];
        }
      }
}

// ---------------- RoPE (YaRN/NTK): qkv bf16 -> qr[64][2048][64], kr[8][2048][64] ----
__global__ __launch_bounds__(256) void k_rope(const u16* __restrict__ qkv,
                                              u16* __restrict__ qrp,
                                              u16* __restrict__ krp) {
  const int t = blockIdx.y;
  const int i = blockIdx.x * 256 + threadIdx.x;  // [0, 2304) = 72 heads * 32 pairs
  const int d = i & 31, hd = i >> 5;
  const float low = 8.0927791f, high = 17.3980236f, conc = 1.3465735903f;
  float freq = powf(150000.0f, (float)d * (1.0f / 32.0f));
  float r01 = fminf(fmaxf(((float)d - low) / (high - low), 0.f), 1.f);
  float invf = (1.0f / (32.0f * freq)) * r01 + (1.0f / freq) * (1.f - r01);
  float ang = (float)t * invf;
  float cc = cosf(ang) * conc;
  float ss = sinf(ang) * conc;
  const u16* src = qkv + (size_t)t * QKVN + (hd < 64 ? hd * 64 : 4096 + (hd - 64) * 64);
  u16* dst = (hd < 64) ? (qrp + ((size_t)hd * SEQ + t) * 64)
                       : (krp + ((size_t)(hd - 64) * SEQ + t) * 64);
  float x1 = bf2f(src[d]), x2 = bf2f(src[d + 32]);
  dst[d] = f2bf(x1 * cc - x2 * ss);
  dst[d + 32] = f2bf(x2 * cc + x1 * ss);
}

// ---------------- V transpose: qkv v-cols -> vt[8][64][2048] bf16 ----------------
__global__ __launch_bounds__(256) void k_vtrans(const u16* __restrict__ qkv,
                                                u16* __restrict__ vt) {
  __shared__ u16 tile[64][72];  // [t_local][d]
  const int t0 = blockIdx.x * 64, h = blockIdx.y;
  for (int s = threadIdx.x; s < 512; s += 256) {
    int r = s >> 3, c8 = (s & 7) * 8;
    uint4 v = *(const uint4*)&qkv[(size_t)(t0 + r) * QKVN + 4608 + h * 64 + c8];
    *(uint4*)&tile[r][c8] = v;
  }
  __syncthreads();
  for (int s = threadIdx.x; s < 512; s += 256) {
    int d = s >> 3, c8 = (s & 7) * 8;
    u32 p0 = tile[c8 + 0][d] | ((u32)tile[c8 + 1][d] << 16);
    u32 p1 = tile[c8 + 2][d] | ((u32)tile[c8 + 3][d] << 16);
    u32 p2 = tile[c8 + 4][d] | ((u32)tile[c8 + 5][d] << 16);
    u32 p3 = tile[c8 + 6][d] | ((u32)tile[c8 + 7][d] << 16);
    *(uint4*)&vt[((size_t)h * 64 + d) * SEQ + t0 + c8] = make_uint4(p0, p1, p2, p3);
  }
}

// ---------------- Attention: sliding window 128 + sink, GQA 8x8 ----------------
// grid (128 qblocks of 16 tokens, 8 kv heads), 512 threads = 8 waves = 8 q-heads.
__global__ __launch_bounds__(512) void k_attn(const u16* __restrict__ qr,
                                              const u16* __restrict__ kr,
                                              const u16* __restrict__ vt,
                                              const float* __restrict__ sinks,
                                              u16* __restrict__ attn) {
  __shared__ u16 lK[144 * 72];       // [key][dim], stride 72
  __shared__ u16 lV[64 * 152];       // [dim][key], stride 152
  __shared__ u16 lP[8 * 16 * 148];   // per-wave [q][key], stride 148
  const int t0 = blockIdx.x * 16;
  const int h = blockIdx.y;
  const int j0 = t0 - 128;
  const int tid = threadIdx.x;
  // stage K rows (zero for j<0)
  for (int s = tid; s < 1152; s += 512) {
    int row = s >> 3, c = s & 7;
    int j = j0 + row;
    uint4 v = make_uint4(0, 0, 0, 0);
    if (j >= 0) v = *(const uint4*)&kr[((size_t)h * SEQ + j) * 64 + c * 8];
    *(uint4*)&lK[row * 72 + c * 8] = v;
  }
  // stage V^T rows (dims), 18 chunks of 8 keys
  for (int s = tid; s < 1152; s += 512) {
    int d = s / 18, c = s - d * 18;
    int jb = j0 + c * 8;
    uint4 v = make_uint4(0, 0, 0, 0);
    if (jb >= 0) v = *(const uint4*)&vt[((size_t)h * 64 + d) * SEQ + jb];
    *(uint4*)&lV[d * 152 + c * 8] = v;
  }
  __syncthreads();
  const int w = tid >> 6, l = tid & 63;
  const int g = l >> 4, q = l & 15;
  const int hq = h * 8 + w;
  const float sink = sinks[hq];
  bf4 qf[4];
  const u16* qrow = qr + ((size_t)hq * SEQ + t0 + q) * 64;
#pragma unroll
  for (int ks = 0; ks < 4; ++ks) qf[ks] = *(const bf4*)&qrow[ks * 16 + g * 4];
  // S = Q K^T over 9 key tiles
  f4 sacc[9];
#pragma unroll
  for (int nt = 0; nt < 9; ++nt) {
    f4 z = {0.f, 0.f, 0.f, 0.f};
    sacc[nt] = z;
#pragma unroll
    for (int ks = 0; ks < 4; ++ks) {
      bf4 kf = *(const bf4*)&lK[(nt * 16 + q) * 72 + ks * 16 + g * 4];
      sacc[nt] = MFMA(qf[ks], kf, sacc[nt]);
    }
  }
  const float NEG = -__builtin_inff();
  float rmax[4] = {NEG, NEG, NEG, NEG};
#pragma unroll
  for (int nt = 0; nt < 9; ++nt)
#pragma unroll
    for (int r = 0; r < 4; ++r) {
      float sv = sacc[nt][r] * 0.125f;
      int it = t0 + g * 4 + r;
      int j = j0 + nt * 16 + q;
      bool ban = (j > it) || (it - j >= 128) || (j < 0);
      sv = ban ? NEG : sv;
      sacc[nt][r] = sv;
      rmax[r] = fmaxf(rmax[r], sv);
    }
#pragma unroll
  for (int r = 0; r < 4; ++r)
#pragma unroll
    for (int m = 1; m < 16; m <<= 1) rmax[r] = fmaxf(rmax[r], __shfl_xor(rmax[r], m));
  float ssum[4];
  u16* pbase = lP + w * (16 * 148);
#pragma unroll
  for (int r = 0; r < 4; ++r) {
    float mf = fmaxf(rmax[r], sink);
    float ps = 0.f;
#pragma unroll
    for (int nt = 0; nt < 9; ++nt) {
      float p = __expf(sacc[nt][r] - mf);  // exp(-inf) = 0 for banned
      pbase[(g * 4 + r) * 148 + nt * 16 + q] = f2bf(p);
      ps += p;
    }
#pragma unroll
    for (int m = 1; m < 16; m <<= 1) ps += __shfl_xor(ps, m);
    ssum[r] = ps + __expf(sink - mf);  // sink joins the denominator only
  }
  // O = P V  (per-wave LDS, same-wave ordering => no barrier)
  f4 oacc[4] = {};
#pragma unroll
  for (int kt = 0; kt < 9; ++kt) {
    bf4 pa = *(const bf4*)&pbase[q * 148 + kt * 16 + g * 4];
#pragma unroll
    for (int nt = 0; nt < 4; ++nt) {
      bf4 vf = *(const bf4*)&lV[(nt * 16 + q) * 152 + kt * 16 + g * 4];
      oacc[nt] = MFMA(pa, vf, oacc[nt]);
    }
  }
#pragma unroll
  for (int nt = 0; nt < 4; ++nt)
#pragma unroll
    for (int r = 0; r < 4; ++r) {
      int row = t0 + g * 4 + r;
      attn[(size_t)row * 4096 + hq * 64 + nt * 16 + q] = f2bf(oacc[nt][r] / ssum[r]);
    }
}

extern "C" void kernel_launch(void* const* d_in, const int* in_sizes, int n_in,
                              void* d_out, int out_size, void* d_ws, size_t ws_size,
                              hipStream_t stream) {
  const float* x = (const float*)d_in[0];
  const float* norm_w = (const float*)d_in[1];
  const float* qkv_w = (const float*)d_in[2];
  const float* out_w = (const float*)d_in[3];
  const float* sinks = (const float*)d_in[4];
  float* out = (float*)d_out;
  char* ws = (char*)d_ws;
  // ws layout (bytes); attn aliases wqkvT (dead after QKV GEMM). total ~107.3 MB
  u16* t     = (u16*)(ws);                  // 2048*2880*2 = 11,796,480
  u16* wqkvT = (u16*)(ws + 11796480);       // 5120*2880*2 = 29,491,200
  u16* woutT = (u16*)(ws + 41287680);       // 2944*4096*2 = 24,117,248 (rows 2880..2943 pad)
  u16* qkv   = (u16*)(ws + 65404928);       // 2048*5120*2 = 20,971,520
  u16* qr    = (u16*)(ws + 86376448);       // 64*2048*64*2 = 16,777,216
  u16* kr    = (u16*)(ws + 103153664);      // 8*2048*64*2 = 2,097,152
  u16* vt    = (u16*)(ws + 105250816);      // 8*64*2048*2 = 2,097,152 -> end 107,347,968
  u16* attn  = (u16*)(ws + 11796480);       // alias wqkvT, 2048*4096*2 = 16,777,216

  k_rmsnorm<<<dim3(2048), dim3(256), 0, stream>>>(x, norm_w, t);
  k_convT<<<dim3(80, 45), dim3(256), 0, stream>>>(qkv_w, wqkvT, 2880, 5120);
  k_convT<<<dim3(45, 64), dim3(256), 0, stream>>>(out_w, woutT, 4096, 2880);
  k_gemm<0><<<dim3(16, 40), dim3(256), 0, stream>>>(t, wqkvT, (void*)qkv, nullptr,
                                                    2048, 5120, 2880);
  k_rope<<<dim3(9, 2048), dim3(256), 0, stream>>>(qkv, qr, kr);
  k_vtrans<<<dim3(32, 8), dim3(256), 0, stream>>>(qkv, vt);
  k_attn<<<dim3(128, 8), dim3(512), 0, stream>>>(qr, kr, vt, sinks, attn);
  k_gemm<1><<<dim3(16, 23), dim3(256), 0, stream>>>(attn, woutT, (void*)out, x,
                                                    2048, 2880, 4096);
}